// Round 13
// baseline (2584.844 us; speedup 1.0000x reference)
//
#include <hip/hip_runtime.h>
#include <cstddef>

// Problem constants
constexpr int B = 8;
constexpr int N = 16384;
constexpr int P = 1024;       // NPOINT
constexpr int S = 32;         // MAX_SAMPLES
constexpr int NSAMP = B * P * S;   // 262144
constexpr float EPS = 1e-5f;
constexpr float INV_N = 1.0f / 262144.0f;

typedef float v2f __attribute__((ext_vector_type(2)));

// Workspace layout (bytes)
//   [0 .. 1048576)          gidx   (B*P*S int32)
//   [1048576 .. +4096)      stats  (float[992] used)
constexpr int ST_S1   = 0;    // 9   input sums
constexpr int ST_S2   = 9;    // 81  input second moments (full 9x9)
constexpr int ST_SUM1 = 96;   // 64  layer1 sum
constexpr int ST_SQ1  = 160;  // 64  layer1 sumsq
constexpr int ST_SUM2 = 224;  // 128 layer2 sum
constexpr int ST_SQ2  = 352;  // 128 layer2 sumsq
constexpr int ST_SC0  = 480;  // 64
constexpr int ST_SH0  = 544;  // 64
constexpr int ST_SC1  = 608;  // 64
constexpr int ST_SH1  = 672;  // 64
constexpr int ST_SC2  = 736;  // 128
constexpr int ST_SH2  = 864;  // 128

// ---------------------------------------------------------------------------
// 1) Farthest point sampling: one block per batch, 512 threads, 32 pts/thread
//    (16 v2f pairs, pair m = points {m*1024+2t, +1}).
//    x,y LDS-resident (SoA 128KB, conflict-free ds_read_b64 — measured 0
//    conflicts in R11); z + dist in registers (64 VGPRs — the size class the
//    allocator kept resident in R9/R11, VGPR=52/88).
//    ROUND-11 POST-MORTEM: six variants (L1-remat / LDS / reg data paths)
//    all land 1557-1855us -> the data path was never the bottleneck. R11
//    counters: ~74% VALU-busy on the 8 active CUs = ~700 VALU instrs/wave/
//    iter, of which only ~300 is distance math. The REST was the tracked
//    argmax: 32 sequential cmp+2cndmask chains + 36-instr u64 DPP + v2f glue.
//    THIS ROUND: strip the hot loop to pure packed arithmetic
//    (sub/mul/add/min/max only, no per-element tracking), then:
//      - wave max via 6-step f32 DPP (12 instrs) + readlane(63) -> bmax
//      - index recovery OFF the VALU path: per slot __ballot(dist==bmax)
//        (32 v_cmp) + ctz/min on the SCALAR pipe (parallel to VALU)
//    Tie-break EXACT: bmax is bit-exactly one of the dist values (IEEE max,
//    no NaN; all dists >= 0 so the DPP 0.0-inject is a safe identity);
//    {i: dist_i==bmax} is precisely the argmax set; min index = first
//    occurrence = jnp.argmax semantics. Cross-wave: u64 key
//    (bits(bmax)<<32)|(16383-minidx), skey LDS + 1 barrier, same as before.
//    contract(off): distance rounding must match numpy exactly.
// ---------------------------------------------------------------------------
__global__ __launch_bounds__(512) void fps_kernel(
    const float* __restrict__ xyz, float* __restrict__ cent) {
#pragma clang fp contract(off)
  const int b = blockIdx.x;
  const int t = threadIdx.x;           // 0..511
  const int wave = t >> 6;             // 0..7
  const int lane = t & 63;
  const float* X = xyz + (size_t)b * N * 3;

  __shared__ float sx[16384];          // 64 KB
  __shared__ float sy[16384];          // 64 KB
  __shared__ unsigned long long skey[2][8];

  // One-time cooperative LDS fill (coalesced over i).
#pragma unroll
  for (int k = 0; k < 32; k++) {
    const int i = t + k * 512;
    sx[i] = X[3 * i + 0];
    sy[i] = X[3 * i + 1];
  }

  // z + dist in registers: pair m covers points i0 = m*1024 + 2t, i0+1.
  v2f pz[16], dist[16];
#pragma unroll
  for (int m = 0; m < 16; m++) {
    const int i0 = m * 1024 + 2 * t;
    pz[m] = (v2f){X[3 * i0 + 2], X[3 * i0 + 5]};
    dist[m] = (v2f){1e10f, 1e10f};
  }

  float cx = X[0], cy = X[1], cz = X[2];   // start index 0
  __syncthreads();                          // LDS fill visible

  for (int j = 0; j < P; j++) {
    if (t == 0) {
      float* co = cent + ((size_t)b * P + j) * 3;
      co[0] = cx; co[1] = cy; co[2] = cz;
    }
    const v2f cx2 = (v2f){cx, cx};
    const v2f cy2 = (v2f){cy, cy};
    const v2f cz2 = (v2f){cz, cz};
    // --- pure packed distance phase: no tracking ---
    v2f rm = (v2f){-1.0f, -1.0f};
#pragma unroll
    for (int m = 0; m < 16; m++) {
      const v2f xv = *(const v2f*)&sx[m * 1024 + 2 * t];   // ds_read_b64
      const v2f yv = *(const v2f*)&sy[m * 1024 + 2 * t];   // ds_read_b64
      v2f dx = xv - cx2;
      v2f dy = yv - cy2;
      v2f dz = pz[m] - cz2;
      v2f d = (dx * dx + dy * dy) + dz * dz;   // elementwise, np rounding
      v2f nd;
      nd.x = fminf(dist[m].x, d.x);
      nd.y = fminf(dist[m].y, d.y);
      dist[m] = nd;
      rm.x = fmaxf(rm.x, nd.x);
      rm.y = fmaxf(rm.y, nd.y);
    }
    float wm = fmaxf(rm.x, rm.y);
    // --- wave max: 6-step f32 DPP cascade (0.0-inject safe: dists >= 0) ---
#define DPP_MAXSTEP(ctrl)                                                   \
    {                                                                       \
      float o_ = __uint_as_float((unsigned)__builtin_amdgcn_update_dpp(     \
          0, (int)__float_as_uint(wm), (ctrl), 0xf, 0xf, false));           \
      wm = fmaxf(wm, o_);                                                   \
    }
    DPP_MAXSTEP(0x111)  // row_shr:1
    DPP_MAXSTEP(0x112)  // row_shr:2
    DPP_MAXSTEP(0x114)  // row_shr:4
    DPP_MAXSTEP(0x118)  // row_shr:8
    DPP_MAXSTEP(0x142)  // row_bcast:15
    DPP_MAXSTEP(0x143)  // row_bcast:31 -> lane 63 = wave max
#undef DPP_MAXSTEP
    const float bmax = __uint_as_float(
        (unsigned)__builtin_amdgcn_readlane((int)__float_as_uint(wm), 63));
    // --- index recovery: ballots (VALU) + ctz/min on scalar pipe ---
    int cand = 0x7FFFFFFF;
#pragma unroll
    for (int m = 0; m < 16; m++) {
      const unsigned long long b0 = __ballot(dist[m].x == bmax);
      const unsigned long long b1 = __ballot(dist[m].y == bmax);
      if (b0 | b1) {
        const int l0 = b0 ? 2 * (int)__builtin_ctzll(b0) : 0x7FFFFFF;
        const int l1 = b1 ? 2 * (int)__builtin_ctzll(b1) + 1 : 0x7FFFFFF;
        const int li = l0 < l1 ? l0 : l1;          // 2*lane + e
        const int ci = m * 1024 + 128 * wave + li; // i = m*1024 + 2t + e
        cand = cand < ci ? cand : ci;
      }
    }
    // wave-uniform key; lane 0 publishes
    const unsigned long long key =
        ((unsigned long long)__float_as_uint(bmax) << 32) |
        (unsigned)(16383 - cand);
    const int buf = j & 1;
    if (lane == 0) skey[buf][wave] = key;
    __syncthreads();
    unsigned long long bkey = skey[buf][0];
#pragma unroll
    for (int w = 1; w < 8; w++) {
      const unsigned long long kk = skey[buf][w];
      if (kk > bkey) bkey = kk;
    }
    const int wi = 16383 - (int)(unsigned)(bkey & 0xFFFFFFFFull);
    // next centroid: x,y broadcast from LDS; z uniform global (parallel)
    cx = sx[wi];
    cy = sy[wi];
    cz = X[3 * wi + 2];
  }
}

// ---------------------------------------------------------------------------
// 2) Ball query: one wave per centroid; first <=32 in-radius indices ascending.
// ---------------------------------------------------------------------------
__global__ __launch_bounds__(256) void ballq_kernel(
    const float* __restrict__ xyz, const float* __restrict__ cent,
    int* __restrict__ gidx) {
#pragma clang fp contract(off)
  const int wid = (blockIdx.x * 256 + threadIdx.x) >> 6;   // 0..8191 (b*P+p)
  const int lane = threadIdx.x & 63;
  const int b = wid >> 10;
  const float* X = xyz + (size_t)b * N * 3;
  const float* c = cent + (size_t)wid * 3;
  const float cx = c[0], cy = c[1], cz = c[2];
  const float cc = (cx * cx + cy * cy) + cz * cz;
  int* g = gidx + (size_t)wid * S;
  const float r2 = 0.2f * 0.2f;

  int cnt = 0;
  for (int base = 0; base < N; base += 64) {
    const int i = base + lane;
    float x = X[3 * i + 0], y = X[3 * i + 1], z = X[3 * i + 2];
    float xx = (x * x + y * y) + z * z;
    float dt = (cx * x + cy * y) + cz * z;
    float d2 = (cc - 2.0f * dt) + xx;            // match reference expanded form
    bool inr = d2 < r2;
    unsigned long long m = __ballot(inr);
    if (inr) {
      int pos = cnt + (int)__popcll(m & ((1ull << lane) - 1ull));
      if (pos < S) g[pos] = i;
    }
    cnt += (int)__popcll(m);
    if (cnt >= S) break;                          // uniform early exit
  }
}

// ---------------------------------------------------------------------------
// Gather one sample's 9 input channels (grouped_xyz - centroid, grouped_pts)
// ---------------------------------------------------------------------------
__device__ __forceinline__ void load_x(
    const float* __restrict__ xyz, const float* __restrict__ points,
    const float* __restrict__ cent, const int* __restrict__ gidx,
    int sample, float x[9]) {
  const int grp = sample >> 5;          // b*P+p
  const int b = grp >> 10;
  const int idx = gidx[sample];
  const float* Xp = xyz + ((size_t)b * N + idx) * 3;
  const float* Pp = points + ((size_t)b * N + idx) * 6;
  const float* C = cent + (size_t)grp * 3;
  x[0] = Xp[0] - C[0];
  x[1] = Xp[1] - C[1];
  x[2] = Xp[2] - C[2];
  x[3] = Pp[0]; x[4] = Pp[1]; x[5] = Pp[2];
  x[6] = Pp[3]; x[7] = Pp[4]; x[8] = Pp[5];
}

// ---------------------------------------------------------------------------
// 3) Input moments (Sum x, Sum x x^T) -> exact layer-0 BN stats analytically.
// ---------------------------------------------------------------------------
__global__ __launch_bounds__(256) void moments_kernel(
    const float* __restrict__ xyz, const float* __restrict__ points,
    const float* __restrict__ cent, const int* __restrict__ gidx,
    float* __restrict__ stats) {
  const int tid = blockIdx.x * 256 + threadIdx.x;   // 8192 threads
  float S1[9], S2[81];
#pragma unroll
  for (int c = 0; c < 9; c++) S1[c] = 0.f;
#pragma unroll
  for (int k = 0; k < 81; k++) S2[k] = 0.f;

  for (int smp = tid; smp < NSAMP; smp += 8192) {
    float x[9];
    load_x(xyz, points, cent, gidx, smp, x);
#pragma unroll
    for (int c = 0; c < 9; c++) {
      S1[c] += x[c];
#pragma unroll
      for (int d = 0; d < 9; d++) S2[c * 9 + d] = fmaf(x[c], x[d], S2[c * 9 + d]);
    }
  }
  const int lane = threadIdx.x & 63;
#pragma unroll
  for (int c = 0; c < 9; c++) {
#pragma unroll
    for (int m = 1; m < 64; m <<= 1) S1[c] += __shfl_xor(S1[c], m, 64);
  }
#pragma unroll
  for (int k = 0; k < 81; k++) {
#pragma unroll
    for (int m = 1; m < 64; m <<= 1) S2[k] += __shfl_xor(S2[k], m, 64);
  }
  if (lane == 0) {
#pragma unroll
    for (int c = 0; c < 9; c++) atomicAdd(&stats[ST_S1 + c], S1[c]);
#pragma unroll
    for (int k = 0; k < 81; k++) atomicAdd(&stats[ST_S2 + k], S2[k]);
  }
}

__global__ void finalize0_kernel(float* __restrict__ stats,
                                 const float* __restrict__ w0,
                                 const float* __restrict__ b0,
                                 const float* __restrict__ g0,
                                 const float* __restrict__ be0) {
  const int o = threadIdx.x;   // 64
  float w[9];
#pragma unroll
  for (int c = 0; c < 9; c++) w[c] = w0[o * 9 + c];
  float dot = 0.f;
#pragma unroll
  for (int c = 0; c < 9; c++) dot += w[c] * stats[ST_S1 + c];
  float quad = 0.f;
#pragma unroll
  for (int c = 0; c < 9; c++)
#pragma unroll
    for (int d = 0; d < 9; d++) quad += w[c] * w[d] * stats[ST_S2 + c * 9 + d];
  const float bb = b0[o];
  const float mean = dot * INV_N + bb;
  const float Ey2 = (quad + 2.0f * bb * dot) * INV_N + bb * bb;
  const float var = Ey2 - mean * mean;
  const float sc = g0[o] / sqrtf(var + EPS);
  stats[ST_SC0 + o] = sc;
  stats[ST_SH0 + o] = be0[o] - mean * sc;
}

// ---------------------------------------------------------------------------
// h0 / h1 recompute helpers (fully unrolled: arrays must stay in registers)
// ---------------------------------------------------------------------------
__device__ __forceinline__ void compute_h0(
    const float x[9], const float* __restrict__ w0, const float* __restrict__ b0,
    const float* __restrict__ stats, float h0[64]) {
  const float* sc = stats + ST_SC0;
  const float* sh = stats + ST_SH0;
#pragma unroll
  for (int o = 0; o < 64; o++) {
    float a = b0[o];
#pragma unroll
    for (int c = 0; c < 9; c++) a = fmaf(w0[o * 9 + c], x[c], a);
    h0[o] = fmaxf(fmaf(a, sc[o], sh[o]), 0.0f);
  }
}

__device__ __forceinline__ void compute_h1(
    const float h0[64], const float* __restrict__ w1, const float* __restrict__ b1,
    const float* __restrict__ stats, float h1[64]) {
  const float* sc = stats + ST_SC1;
  const float* sh = stats + ST_SH1;
#pragma unroll
  for (int o = 0; o < 64; o++) {
    float a = b1[o];
#pragma unroll
    for (int c = 0; c < 64; c++) a = fmaf(w1[o * 64 + c], h0[c], a);
    h1[o] = fmaxf(fmaf(a, sc[o], sh[o]), 0.0f);
  }
}

// ---------------------------------------------------------------------------
// 4) Layer-1 pre-BN stats: recompute h0, accumulate per-channel sum/sumsq.
// ---------------------------------------------------------------------------
__global__ __launch_bounds__(256) void pass2_kernel(
    const float* __restrict__ xyz, const float* __restrict__ points,
    const float* __restrict__ cent, const int* __restrict__ gidx,
    const float* __restrict__ w0, const float* __restrict__ b0,
    const float* __restrict__ w1, const float* __restrict__ b1,
    float* __restrict__ stats) {
  const int tid = blockIdx.x * 256 + threadIdx.x;
  float x[9];
  load_x(xyz, points, cent, gidx, tid, x);
  float h0[64];
  compute_h0(x, w0, b0, stats, h0);

  __shared__ float ssum[4][64], ssq[4][64];
  const int wv = threadIdx.x >> 6, lane = threadIdx.x & 63;
#pragma unroll 1
  for (int o = 0; o < 64; o++) {
    float a = b1[o];
#pragma unroll
    for (int c = 0; c < 64; c++) a = fmaf(w1[o * 64 + c], h0[c], a);
    float s = a, q = a * a;
#pragma unroll
    for (int m = 1; m < 64; m <<= 1) {
      s += __shfl_xor(s, m, 64);
      q += __shfl_xor(q, m, 64);
    }
    if (lane == 0) { ssum[wv][o] = s; ssq[wv][o] = q; }
  }
  __syncthreads();
  if (threadIdx.x < 64) {
    const int o = threadIdx.x;
    float s = ssum[0][o] + ssum[1][o] + ssum[2][o] + ssum[3][o];
    float q = ssq[0][o] + ssq[1][o] + ssq[2][o] + ssq[3][o];
    atomicAdd(&stats[ST_SUM1 + o], s);
    atomicAdd(&stats[ST_SQ1 + o], q);
  }
}

__global__ void finalize1_kernel(float* __restrict__ stats,
                                 const float* __restrict__ g1,
                                 const float* __restrict__ be1) {
  const int o = threadIdx.x;   // 64
  const float mean = stats[ST_SUM1 + o] * INV_N;
  const float var = stats[ST_SQ1 + o] * INV_N - mean * mean;
  const float sc = g1[o] / sqrtf(var + EPS);
  stats[ST_SC1 + o] = sc;
  stats[ST_SH1 + o] = be1[o] - mean * sc;
}

// ---------------------------------------------------------------------------
// 5) Layer-2 pre-BN stats: recompute h0,h1, accumulate 128-channel sum/sumsq.
// ---------------------------------------------------------------------------
__global__ __launch_bounds__(256) void pass3_kernel(
    const float* __restrict__ xyz, const float* __restrict__ points,
    const float* __restrict__ cent, const int* __restrict__ gidx,
    const float* __restrict__ w0, const float* __restrict__ b0,
    const float* __restrict__ w1, const float* __restrict__ b1,
    const float* __restrict__ w2, const float* __restrict__ b2,
    float* __restrict__ stats) {
  const int tid = blockIdx.x * 256 + threadIdx.x;
  float x[9];
  load_x(xyz, points, cent, gidx, tid, x);
  float h0[64];
  compute_h0(x, w0, b0, stats, h0);
  float h1[64];
  compute_h1(h0, w1, b1, stats, h1);

  __shared__ float ssum[4][128], ssq[4][128];
  const int wv = threadIdx.x >> 6, lane = threadIdx.x & 63;
#pragma unroll 1
  for (int o = 0; o < 128; o++) {
    float a = b2[o];
#pragma unroll
    for (int c = 0; c < 64; c++) a = fmaf(w2[o * 64 + c], h1[c], a);
    float s = a, q = a * a;
#pragma unroll
    for (int m = 1; m < 64; m <<= 1) {
      s += __shfl_xor(s, m, 64);
      q += __shfl_xor(q, m, 64);
    }
    if (lane == 0) { ssum[wv][o] = s; ssq[wv][o] = q; }
  }
  __syncthreads();
  if (threadIdx.x < 128) {
    const int o = threadIdx.x;
    float s = ssum[0][o] + ssum[1][o] + ssum[2][o] + ssum[3][o];
    float q = ssq[0][o] + ssq[1][o] + ssq[2][o] + ssq[3][o];
    atomicAdd(&stats[ST_SUM2 + o], s);
    atomicAdd(&stats[ST_SQ2 + o], q);
  }
}

__global__ void finalize2_kernel(float* __restrict__ stats,
                                 const float* __restrict__ g2,
                                 const float* __restrict__ be2) {
  const int o = threadIdx.x;   // 128
  const float mean = stats[ST_SUM2 + o] * INV_N;
  const float var = stats[ST_SQ2 + o] * INV_N - mean * mean;
  const float sc = g2[o] / sqrtf(var + EPS);
  stats[ST_SC2 + o] = sc;
  stats[ST_SH2 + o] = be2[o] - mean * sc;
}

// ---------------------------------------------------------------------------
// 6) Final pass: recompute chain, BN2+ReLU, max over S via half-wave shuffles.
// ---------------------------------------------------------------------------
__global__ __launch_bounds__(256) void pass4_kernel(
    const float* __restrict__ xyz, const float* __restrict__ points,
    const float* __restrict__ cent, const int* __restrict__ gidx,
    const float* __restrict__ w0, const float* __restrict__ b0,
    const float* __restrict__ w1, const float* __restrict__ b1,
    const float* __restrict__ w2, const float* __restrict__ b2,
    const float* __restrict__ stats, float* __restrict__ outnp) {
  const int wid = (blockIdx.x * 256 + threadIdx.x) >> 6;  // 0..4095
  const int lane = threadIdx.x & 63;
  const int grp = wid * 2 + (lane >> 5);                  // 0..8191
  const int s = lane & 31;
  const int sample = grp * 32 + s;

  float x[9];
  load_x(xyz, points, cent, gidx, sample, x);
  float h0[64];
  compute_h0(x, w0, b0, stats, h0);
  float h1[64];
  compute_h1(h0, w1, b1, stats, h1);

  const float* sc2 = stats + ST_SC2;
  const float* sh2 = stats + ST_SH2;
#pragma unroll 1
  for (int o = 0; o < 128; o++) {
    float a = b2[o];
#pragma unroll
    for (int c = 0; c < 64; c++) a = fmaf(w2[o * 64 + c], h1[c], a);
    float v = fmaxf(fmaf(a, sc2[o], sh2[o]), 0.0f);
#pragma unroll
    for (int m = 1; m < 32; m <<= 1) v = fmaxf(v, __shfl_xor(v, m, 64));
    if ((lane & 31) == 0) outnp[(size_t)grp * 128 + o] = v;
  }
}

// ---------------------------------------------------------------------------
extern "C" void kernel_launch(void* const* d_in, const int* in_sizes, int n_in,
                              void* d_out, int out_size, void* d_ws,
                              size_t ws_size, hipStream_t stream) {
  const float* xyz = (const float*)d_in[0];
  const float* points = (const float*)d_in[1];
  const float* w0 = (const float*)d_in[2];
  const float* b0 = (const float*)d_in[3];
  const float* g0 = (const float*)d_in[4];
  const float* be0 = (const float*)d_in[5];
  const float* w1 = (const float*)d_in[6];
  const float* b1 = (const float*)d_in[7];
  const float* g1 = (const float*)d_in[8];
  const float* be1 = (const float*)d_in[9];
  const float* w2 = (const float*)d_in[10];
  const float* b2 = (const float*)d_in[11];
  const float* g2 = (const float*)d_in[12];
  const float* be2 = (const float*)d_in[13];

  float* out = (float*)d_out;
  float* cent = out;                    // (B,P,3)
  float* outnp = out + B * P * 3;       // (B,P,128)

  const size_t GIDX_BYTES = (size_t)NSAMP * sizeof(int);      // 1 MiB
  const size_t STATS_BYTES = 4096;
  if (ws_size < GIDX_BYTES + STATS_BYTES) return;             // defensive
  int* gidx = (int*)d_ws;
  float* stats = (float*)((char*)d_ws + GIDX_BYTES);

  hipMemsetAsync(d_ws, 0, GIDX_BYTES + STATS_BYTES, stream);

  fps_kernel<<<B, 512, 0, stream>>>(xyz, cent);
  ballq_kernel<<<(B * P) / 4, 256, 0, stream>>>(xyz, cent, gidx);
  moments_kernel<<<32, 256, 0, stream>>>(xyz, points, cent, gidx, stats);
  finalize0_kernel<<<1, 64, 0, stream>>>(stats, w0, b0, g0, be0);
  pass2_kernel<<<NSAMP / 256, 256, 0, stream>>>(xyz, points, cent, gidx,
                                                w0, b0, w1, b1, stats);
  finalize1_kernel<<<1, 64, 0, stream>>>(stats, g1, be1);
  pass3_kernel<<<NSAMP / 256, 256, 0, stream>>>(xyz, points, cent, gidx,
                                                w0, b0, w1, b1, w2, b2, stats);
  finalize2_kernel<<<1, 128, 0, stream>>>(stats, g2, be2);
  pass4_kernel<<<NSAMP / 256, 256, 0, stream>>>(xyz, points, cent, gidx,
                                                w0, b0, w1, b1, w2, b2, stats,
                                                outnp);
}

// Round 14
// 2283.751 us; speedup vs baseline: 1.1318x; 1.1318x over previous
//
#include <hip/hip_runtime.h>
#include <cstddef>

// Problem constants
constexpr int B = 8;
constexpr int N = 16384;
constexpr int P = 1024;       // NPOINT
constexpr int S = 32;         // MAX_SAMPLES
constexpr int NSAMP = B * P * S;   // 262144
constexpr float EPS = 1e-5f;
constexpr float INV_N = 1.0f / 262144.0f;

typedef float v2f __attribute__((ext_vector_type(2)));

// Workspace layout (bytes)
//   [0 .. 1048576)          gidx   (B*P*S int32)
//   [1048576 .. +4096)      stats  (float[992] used)
constexpr int ST_S1   = 0;    // 9   input sums
constexpr int ST_S2   = 9;    // 81  input second moments (full 9x9)
constexpr int ST_SUM1 = 96;   // 64  layer1 sum
constexpr int ST_SQ1  = 160;  // 64  layer1 sumsq
constexpr int ST_SUM2 = 224;  // 128 layer2 sum
constexpr int ST_SQ2  = 352;  // 128 layer2 sumsq
constexpr int ST_SC0  = 480;  // 64
constexpr int ST_SH0  = 544;  // 64
constexpr int ST_SC1  = 608;  // 64
constexpr int ST_SH1  = 672;  // 64
constexpr int ST_SC2  = 736;  // 128
constexpr int ST_SH2  = 864;  // 128

// Cooperative LDS staging (blockDim.x == 256 in all pass kernels)
#define STAGE256(dst, src, n)                                               \
  for (int i_ = threadIdx.x; i_ < (n); i_ += 256) (dst)[i_] = (src)[i_];

// ---------------------------------------------------------------------------
// DPP full-wave max reduction on a u64 key.
// row_shr:1/2/4/8 then row_bcast:15, row_bcast:31 -> lane 63 holds the max
// over all 64 lanes. old=0 is the identity (keys always > 0).
// ---------------------------------------------------------------------------
__device__ __forceinline__ unsigned long long wave_max_key_dpp(
    unsigned long long key) {
#define DPP_STEP(ctrl)                                                      \
  {                                                                         \
    unsigned lo = (unsigned)key;                                            \
    unsigned hi = (unsigned)(key >> 32);                                    \
    unsigned lo2 = (unsigned)__builtin_amdgcn_update_dpp(                   \
        0, (int)lo, (ctrl), 0xf, 0xf, false);                               \
    unsigned hi2 = (unsigned)__builtin_amdgcn_update_dpp(                   \
        0, (int)hi, (ctrl), 0xf, 0xf, false);                               \
    unsigned long long k2 = ((unsigned long long)hi2 << 32) | lo2;          \
    if (k2 > key) key = k2;                                                 \
  }
  DPP_STEP(0x111);  // row_shr:1
  DPP_STEP(0x112);  // row_shr:2
  DPP_STEP(0x114);  // row_shr:4
  DPP_STEP(0x118);  // row_shr:8
  DPP_STEP(0x142);  // row_bcast:15
  DPP_STEP(0x143);  // row_bcast:31 -> lane63 = max(all)
#undef DPP_STEP
  return key;
}

// ---------------------------------------------------------------------------
// 1) Farthest point sampling — EXACT R8 config (best measured: 1557us).
//    512 threads, 32 pts/thread v2f[16], global-remat coords, tracked u64
//    argmax, 96KB LDS occupancy cap. R13 RECORD: 7 fps variants all in
//    [1557,1855]; R8 is the local optimum (79% VALU-busy on active CUs).
//    R13's ballot-argmax cut VALU issue 25% but ADDED serial latency
//    (dur rose) -> at 2 waves/SIMD, issue-count trades into stall. Revert.
// ---------------------------------------------------------------------------
__global__ __launch_bounds__(512) void fps_kernel(
    const float* __restrict__ xyz, float* __restrict__ cent) {
#pragma clang fp contract(off)
  const int b = blockIdx.x;
  const int t = threadIdx.x;           // 0..511
  const int wave = t >> 6;             // 0..7
  const float* X = xyz + (size_t)b * N * 3;

  // Occupancy limiter: 96KB forces 1 block/CU. Never written at runtime
  // (guard is data-dependent false), but opaque to the compiler.
  __shared__ float lds_force[24576];
  __shared__ unsigned long long skey[2][8];

  // element e of pair m <-> k = 2m+e <-> point index t + k*512
  v2f px[16], py[16], pz[16], dist[16];
#pragma unroll
  for (int m = 0; m < 16; m++) {
    int i0 = t + (2 * m) * 512;
    int i1 = t + (2 * m + 1) * 512;
    px[m] = (v2f){X[3 * i0 + 0], X[3 * i1 + 0]};
    py[m] = (v2f){X[3 * i0 + 1], X[3 * i1 + 1]};
    pz[m] = (v2f){X[3 * i0 + 2], X[3 * i1 + 2]};
    dist[m] = (v2f){1e10f, 1e10f};
  }

  float cx = X[0], cy = X[1], cz = X[2];   // start index 0

  // Keep lds_force alive: coords are uniform[0,1), so cx > 1e29f is never
  // true at runtime, but the compiler cannot prove it (loaded data).
  if (cx > 1e29f) {
    lds_force[t] = cy;
    cz += lds_force[t ^ 1];
  }

  for (int j = 0; j < P; j++) {
    if (t == 0) {
      float* co = cent + ((size_t)b * P + j) * 3;
      co[0] = cx; co[1] = cy; co[2] = cz;
    }
    const v2f cx2 = (v2f){cx, cx};
    const v2f cy2 = (v2f){cy, cy};
    const v2f cz2 = (v2f){cz, cz};
    float best = -1.0f;
    int bk = 0;
#pragma unroll
    for (int m = 0; m < 16; m++) {
      v2f dx = px[m] - cx2;
      v2f dy = py[m] - cy2;
      v2f dz = pz[m] - cz2;
      v2f d = (dx * dx + dy * dy) + dz * dz;   // elementwise, np rounding
      v2f nd;
      nd.x = fminf(dist[m].x, d.x);
      nd.y = fminf(dist[m].y, d.y);
      dist[m] = nd;
      if (nd.x > best) { best = nd.x; bk = 2 * m; }      // ascending k order
      if (nd.y > best) { best = nd.y; bk = 2 * m + 1; }
    }
    const int bi = t + bk * 512;
    unsigned long long key =
        ((unsigned long long)__float_as_uint(best) << 32) |
        (unsigned)(16383 - bi);
    key = wave_max_key_dpp(key);            // lane 63 holds the wave max
    const int buf = j & 1;
    if ((t & 63) == 63) skey[buf][wave] = key;
    __syncthreads();
    unsigned long long bkey = skey[buf][0];
#pragma unroll
    for (int w = 1; w < 8; w++) {
      unsigned long long kk = skey[buf][w];
      if (kk > bkey) bkey = kk;
    }
    const int wi = 16383 - (int)(unsigned)(bkey & 0xFFFFFFFFull);
    // uniform broadcast load of next centroid's coords (L1/L2 hit)
    cx = X[3 * wi + 0];
    cy = X[3 * wi + 1];
    cz = X[3 * wi + 2];
  }
}

// ---------------------------------------------------------------------------
// 2) Ball query: one wave per centroid; first <=32 in-radius indices ascending.
// ---------------------------------------------------------------------------
__global__ __launch_bounds__(256) void ballq_kernel(
    const float* __restrict__ xyz, const float* __restrict__ cent,
    int* __restrict__ gidx) {
#pragma clang fp contract(off)
  const int wid = (blockIdx.x * 256 + threadIdx.x) >> 6;   // 0..8191 (b*P+p)
  const int lane = threadIdx.x & 63;
  const int b = wid >> 10;
  const float* X = xyz + (size_t)b * N * 3;
  const float* c = cent + (size_t)wid * 3;
  const float cx = c[0], cy = c[1], cz = c[2];
  const float cc = (cx * cx + cy * cy) + cz * cz;
  int* g = gidx + (size_t)wid * S;
  const float r2 = 0.2f * 0.2f;

  int cnt = 0;
  for (int base = 0; base < N; base += 64) {
    const int i = base + lane;
    float x = X[3 * i + 0], y = X[3 * i + 1], z = X[3 * i + 2];
    float xx = (x * x + y * y) + z * z;
    float dt = (cx * x + cy * y) + cz * z;
    float d2 = (cc - 2.0f * dt) + xx;            // match reference expanded form
    bool inr = d2 < r2;
    unsigned long long m = __ballot(inr);
    if (inr) {
      int pos = cnt + (int)__popcll(m & ((1ull << lane) - 1ull));
      if (pos < S) g[pos] = i;
    }
    cnt += (int)__popcll(m);
    if (cnt >= S) break;                          // uniform early exit
  }
}

// ---------------------------------------------------------------------------
// Gather one sample's 9 input channels (grouped_xyz - centroid, grouped_pts)
// ---------------------------------------------------------------------------
__device__ __forceinline__ void load_x(
    const float* __restrict__ xyz, const float* __restrict__ points,
    const float* __restrict__ cent, const int* __restrict__ gidx,
    int sample, float x[9]) {
  const int grp = sample >> 5;          // b*P+p
  const int b = grp >> 10;
  const int idx = gidx[sample];
  const float* Xp = xyz + ((size_t)b * N + idx) * 3;
  const float* Pp = points + ((size_t)b * N + idx) * 6;
  const float* C = cent + (size_t)grp * 3;
  x[0] = Xp[0] - C[0];
  x[1] = Xp[1] - C[1];
  x[2] = Xp[2] - C[2];
  x[3] = Pp[0]; x[4] = Pp[1]; x[5] = Pp[2];
  x[6] = Pp[3]; x[7] = Pp[4]; x[8] = Pp[5];
}

// ---------------------------------------------------------------------------
// 3) Input moments (Sum x, Sum x x^T) -> exact layer-0 BN stats analytically.
// ---------------------------------------------------------------------------
__global__ __launch_bounds__(256) void moments_kernel(
    const float* __restrict__ xyz, const float* __restrict__ points,
    const float* __restrict__ cent, const int* __restrict__ gidx,
    float* __restrict__ stats) {
  const int tid = blockIdx.x * 256 + threadIdx.x;   // 8192 threads
  float S1[9], S2[81];
#pragma unroll
  for (int c = 0; c < 9; c++) S1[c] = 0.f;
#pragma unroll
  for (int k = 0; k < 81; k++) S2[k] = 0.f;

  for (int smp = tid; smp < NSAMP; smp += 8192) {
    float x[9];
    load_x(xyz, points, cent, gidx, smp, x);
#pragma unroll
    for (int c = 0; c < 9; c++) {
      S1[c] += x[c];
#pragma unroll
      for (int d = 0; d < 9; d++) S2[c * 9 + d] = fmaf(x[c], x[d], S2[c * 9 + d]);
    }
  }
  const int lane = threadIdx.x & 63;
#pragma unroll
  for (int c = 0; c < 9; c++) {
#pragma unroll
    for (int m = 1; m < 64; m <<= 1) S1[c] += __shfl_xor(S1[c], m, 64);
  }
#pragma unroll
  for (int k = 0; k < 81; k++) {
#pragma unroll
    for (int m = 1; m < 64; m <<= 1) S2[k] += __shfl_xor(S2[k], m, 64);
  }
  if (lane == 0) {
#pragma unroll
    for (int c = 0; c < 9; c++) atomicAdd(&stats[ST_S1 + c], S1[c]);
#pragma unroll
    for (int k = 0; k < 81; k++) atomicAdd(&stats[ST_S2 + k], S2[k]);
  }
}

__global__ void finalize0_kernel(float* __restrict__ stats,
                                 const float* __restrict__ w0,
                                 const float* __restrict__ b0,
                                 const float* __restrict__ g0,
                                 const float* __restrict__ be0) {
  const int o = threadIdx.x;   // 64
  float w[9];
#pragma unroll
  for (int c = 0; c < 9; c++) w[c] = w0[o * 9 + c];
  float dot = 0.f;
#pragma unroll
  for (int c = 0; c < 9; c++) dot += w[c] * stats[ST_S1 + c];
  float quad = 0.f;
#pragma unroll
  for (int c = 0; c < 9; c++)
#pragma unroll
    for (int d = 0; d < 9; d++) quad += w[c] * w[d] * stats[ST_S2 + c * 9 + d];
  const float bb = b0[o];
  const float mean = dot * INV_N + bb;
  const float Ey2 = (quad + 2.0f * bb * dot) * INV_N + bb * bb;
  const float var = Ey2 - mean * mean;
  const float sc = g0[o] / sqrtf(var + EPS);
  stats[ST_SC0 + o] = sc;
  stats[ST_SH0 + o] = be0[o] - mean * sc;
}

// ---------------------------------------------------------------------------
// LDS-resident h0/h1 helpers. ROUND-13 CHANGE: weight reads come from LDS
// (uniform-address ds_read broadcast, float4 rows) instead of per-lane
// global loads. EVIDENCE: R4 profile showed pass3 FETCH=24.4GB/dispatch =
// 262144 thr x 12.9K weight floats — the w loads compile to per-lane VMEM,
// ~12.9K VMEM issues/thread; non-fps time stuck at 753us across all rounds
// (model says ~150us for the math alone). Staging removes VMEM from the
// inner loops entirely. fmaf ORDER IS UNCHANGED -> values bit-identical.
// ---------------------------------------------------------------------------
__device__ __forceinline__ void compute_h0_l(
    const float x[9], const float* lw0, const float* lb0,
    const float* lsc0, const float* lsh0, float h0[64]) {
#pragma unroll
  for (int o = 0; o < 64; o++) {
    float a = lb0[o];
#pragma unroll
    for (int c = 0; c < 9; c++) a = fmaf(lw0[o * 9 + c], x[c], a);
    h0[o] = fmaxf(fmaf(a, lsc0[o], lsh0[o]), 0.0f);
  }
}

__device__ __forceinline__ float dot64_l(const float* lwrow, const float h[64],
                                         float a) {
  const float4* wr = (const float4*)lwrow;
#pragma unroll
  for (int c4 = 0; c4 < 16; c4++) {
    const float4 wv = wr[c4];
    a = fmaf(wv.x, h[4 * c4 + 0], a);
    a = fmaf(wv.y, h[4 * c4 + 1], a);
    a = fmaf(wv.z, h[4 * c4 + 2], a);
    a = fmaf(wv.w, h[4 * c4 + 3], a);
  }
  return a;
}

__device__ __forceinline__ void compute_h1_l(
    const float h0[64], const float* lw1, const float* lb1,
    const float* lsc1, const float* lsh1, float h1[64]) {
#pragma unroll
  for (int o = 0; o < 64; o++) {
    float a = dot64_l(&lw1[o * 64], h0, lb1[o]);
    h1[o] = fmaxf(fmaf(a, lsc1[o], lsh1[o]), 0.0f);
  }
}

// ---------------------------------------------------------------------------
// 4) Layer-1 pre-BN stats: recompute h0, accumulate per-channel sum/sumsq.
//    Weights/BN staged in LDS (~22KB -> 7 blocks/CU).
// ---------------------------------------------------------------------------
__global__ __launch_bounds__(256) void pass2_kernel(
    const float* __restrict__ xyz, const float* __restrict__ points,
    const float* __restrict__ cent, const int* __restrict__ gidx,
    const float* __restrict__ w0, const float* __restrict__ b0,
    const float* __restrict__ w1, const float* __restrict__ b1,
    float* __restrict__ stats) {
  __shared__ __attribute__((aligned(16))) float lw1[4096];
  __shared__ float lw0[576], lb0v[64], lsc0[64], lsh0[64], lb1v[64];
  __shared__ float ssum[4][64], ssq[4][64];
  STAGE256(lw1, w1, 4096)
  STAGE256(lw0, w0, 576)
  STAGE256(lb0v, b0, 64)
  STAGE256(lsc0, stats + ST_SC0, 64)
  STAGE256(lsh0, stats + ST_SH0, 64)
  STAGE256(lb1v, b1, 64)
  __syncthreads();

  const int tid = blockIdx.x * 256 + threadIdx.x;
  float x[9];
  load_x(xyz, points, cent, gidx, tid, x);
  float h0[64];
  compute_h0_l(x, lw0, lb0v, lsc0, lsh0, h0);

  const int wv = threadIdx.x >> 6, lane = threadIdx.x & 63;
#pragma unroll 1
  for (int o = 0; o < 64; o++) {
    float a = dot64_l(&lw1[o * 64], h0, lb1v[o]);
    float s = a, q = a * a;
#pragma unroll
    for (int m = 1; m < 64; m <<= 1) {
      s += __shfl_xor(s, m, 64);
      q += __shfl_xor(q, m, 64);
    }
    if (lane == 0) { ssum[wv][o] = s; ssq[wv][o] = q; }
  }
  __syncthreads();
  if (threadIdx.x < 64) {
    const int o = threadIdx.x;
    float s = ssum[0][o] + ssum[1][o] + ssum[2][o] + ssum[3][o];
    float q = ssq[0][o] + ssq[1][o] + ssq[2][o] + ssq[3][o];
    atomicAdd(&stats[ST_SUM1 + o], s);
    atomicAdd(&stats[ST_SQ1 + o], q);
  }
}

__global__ void finalize1_kernel(float* __restrict__ stats,
                                 const float* __restrict__ g1,
                                 const float* __restrict__ be1) {
  const int o = threadIdx.x;   // 64
  const float mean = stats[ST_SUM1 + o] * INV_N;
  const float var = stats[ST_SQ1 + o] * INV_N - mean * mean;
  const float sc = g1[o] / sqrtf(var + EPS);
  stats[ST_SC1 + o] = sc;
  stats[ST_SH1 + o] = be1[o] - mean * sc;
}

// ---------------------------------------------------------------------------
// 5) Layer-2 pre-BN stats: recompute h0,h1, accumulate 128-ch sum/sumsq.
//    All weights staged in LDS (~58KB -> 2 blocks/CU; VALU-bound, OK).
// ---------------------------------------------------------------------------
__global__ __launch_bounds__(256) void pass3_kernel(
    const float* __restrict__ xyz, const float* __restrict__ points,
    const float* __restrict__ cent, const int* __restrict__ gidx,
    const float* __restrict__ w0, const float* __restrict__ b0,
    const float* __restrict__ w1, const float* __restrict__ b1,
    const float* __restrict__ w2, const float* __restrict__ b2,
    float* __restrict__ stats) {
  __shared__ __attribute__((aligned(16))) float lw1[4096];
  __shared__ __attribute__((aligned(16))) float lw2[8192];
  __shared__ float lw0[576], lb0v[64], lsc0[64], lsh0[64];
  __shared__ float lb1v[64], lsc1[64], lsh1[64], lb2v[128];
  __shared__ float ssum[4][128], ssq[4][128];
  STAGE256(lw1, w1, 4096)
  STAGE256(lw2, w2, 8192)
  STAGE256(lw0, w0, 576)
  STAGE256(lb0v, b0, 64)
  STAGE256(lsc0, stats + ST_SC0, 64)
  STAGE256(lsh0, stats + ST_SH0, 64)
  STAGE256(lb1v, b1, 64)
  STAGE256(lsc1, stats + ST_SC1, 64)
  STAGE256(lsh1, stats + ST_SH1, 64)
  STAGE256(lb2v, b2, 128)
  __syncthreads();

  const int tid = blockIdx.x * 256 + threadIdx.x;
  float x[9];
  load_x(xyz, points, cent, gidx, tid, x);
  float h0[64];
  compute_h0_l(x, lw0, lb0v, lsc0, lsh0, h0);
  float h1[64];
  compute_h1_l(h0, lw1, lb1v, lsc1, lsh1, h1);

  const int wv = threadIdx.x >> 6, lane = threadIdx.x & 63;
#pragma unroll 1
  for (int o = 0; o < 128; o++) {
    float a = dot64_l(&lw2[o * 64], h1, lb2v[o]);
    float s = a, q = a * a;
#pragma unroll
    for (int m = 1; m < 64; m <<= 1) {
      s += __shfl_xor(s, m, 64);
      q += __shfl_xor(q, m, 64);
    }
    if (lane == 0) { ssum[wv][o] = s; ssq[wv][o] = q; }
  }
  __syncthreads();
  if (threadIdx.x < 128) {
    const int o = threadIdx.x;
    float s = ssum[0][o] + ssum[1][o] + ssum[2][o] + ssum[3][o];
    float q = ssq[0][o] + ssq[1][o] + ssq[2][o] + ssq[3][o];
    atomicAdd(&stats[ST_SUM2 + o], s);
    atomicAdd(&stats[ST_SQ2 + o], q);
  }
}

__global__ void finalize2_kernel(float* __restrict__ stats,
                                 const float* __restrict__ g2,
                                 const float* __restrict__ be2) {
  const int o = threadIdx.x;   // 128
  const float mean = stats[ST_SUM2 + o] * INV_N;
  const float var = stats[ST_SQ2 + o] * INV_N - mean * mean;
  const float sc = g2[o] / sqrtf(var + EPS);
  stats[ST_SC2 + o] = sc;
  stats[ST_SH2 + o] = be2[o] - mean * sc;
}

// ---------------------------------------------------------------------------
// 6) Final pass: recompute chain, BN2+ReLU, max over S via half-wave shuffles.
//    All weights + BN staged in LDS (~54KB -> 2 blocks/CU).
// ---------------------------------------------------------------------------
__global__ __launch_bounds__(256) void pass4_kernel(
    const float* __restrict__ xyz, const float* __restrict__ points,
    const float* __restrict__ cent, const int* __restrict__ gidx,
    const float* __restrict__ w0, const float* __restrict__ b0,
    const float* __restrict__ w1, const float* __restrict__ b1,
    const float* __restrict__ w2, const float* __restrict__ b2,
    const float* __restrict__ stats, float* __restrict__ outnp) {
  __shared__ __attribute__((aligned(16))) float lw1[4096];
  __shared__ __attribute__((aligned(16))) float lw2[8192];
  __shared__ float lw0[576], lb0v[64], lsc0[64], lsh0[64];
  __shared__ float lb1v[64], lsc1[64], lsh1[64];
  __shared__ float lb2v[128], lsc2[128], lsh2[128];
  STAGE256(lw1, w1, 4096)
  STAGE256(lw2, w2, 8192)
  STAGE256(lw0, w0, 576)
  STAGE256(lb0v, b0, 64)
  STAGE256(lsc0, stats + ST_SC0, 64)
  STAGE256(lsh0, stats + ST_SH0, 64)
  STAGE256(lb1v, b1, 64)
  STAGE256(lsc1, stats + ST_SC1, 64)
  STAGE256(lsh1, stats + ST_SH1, 64)
  STAGE256(lb2v, b2, 128)
  STAGE256(lsc2, stats + ST_SC2, 128)
  STAGE256(lsh2, stats + ST_SH2, 128)
  __syncthreads();

  const int wid = (blockIdx.x * 256 + threadIdx.x) >> 6;  // 0..4095
  const int lane = threadIdx.x & 63;
  const int grp = wid * 2 + (lane >> 5);                  // 0..8191
  const int s = lane & 31;
  const int sample = grp * 32 + s;

  float x[9];
  load_x(xyz, points, cent, gidx, sample, x);
  float h0[64];
  compute_h0_l(x, lw0, lb0v, lsc0, lsh0, h0);
  float h1[64];
  compute_h1_l(h0, lw1, lb1v, lsc1, lsh1, h1);

#pragma unroll 1
  for (int o = 0; o < 128; o++) {
    float a = dot64_l(&lw2[o * 64], h1, lb2v[o]);
    float v = fmaxf(fmaf(a, lsc2[o], lsh2[o]), 0.0f);
#pragma unroll
    for (int m = 1; m < 32; m <<= 1) v = fmaxf(v, __shfl_xor(v, m, 64));
    if ((lane & 31) == 0) outnp[(size_t)grp * 128 + o] = v;
  }
}

// ---------------------------------------------------------------------------
extern "C" void kernel_launch(void* const* d_in, const int* in_sizes, int n_in,
                              void* d_out, int out_size, void* d_ws,
                              size_t ws_size, hipStream_t stream) {
  const float* xyz = (const float*)d_in[0];
  const float* points = (const float*)d_in[1];
  const float* w0 = (const float*)d_in[2];
  const float* b0 = (const float*)d_in[3];
  const float* g0 = (const float*)d_in[4];
  const float* be0 = (const float*)d_in[5];
  const float* w1 = (const float*)d_in[6];
  const float* b1 = (const float*)d_in[7];
  const float* g1 = (const float*)d_in[8];
  const float* be1 = (const float*)d_in[9];
  const float* w2 = (const float*)d_in[10];
  const float* b2 = (const float*)d_in[11];
  const float* g2 = (const float*)d_in[12];
  const float* be2 = (const float*)d_in[13];

  float* out = (float*)d_out;
  float* cent = out;                    // (B,P,3)
  float* outnp = out + B * P * 3;       // (B,P,128)

  const size_t GIDX_BYTES = (size_t)NSAMP * sizeof(int);      // 1 MiB
  const size_t STATS_BYTES = 4096;
  if (ws_size < GIDX_BYTES + STATS_BYTES) return;             // defensive
  int* gidx = (int*)d_ws;
  float* stats = (float*)((char*)d_ws + GIDX_BYTES);

  hipMemsetAsync(d_ws, 0, GIDX_BYTES + STATS_BYTES, stream);

  fps_kernel<<<B, 512, 0, stream>>>(xyz, cent);
  ballq_kernel<<<(B * P) / 4, 256, 0, stream>>>(xyz, cent, gidx);
  moments_kernel<<<32, 256, 0, stream>>>(xyz, points, cent, gidx, stats);
  finalize0_kernel<<<1, 64, 0, stream>>>(stats, w0, b0, g0, be0);
  pass2_kernel<<<NSAMP / 256, 256, 0, stream>>>(xyz, points, cent, gidx,
                                                w0, b0, w1, b1, stats);
  finalize1_kernel<<<1, 64, 0, stream>>>(stats, g1, be1);
  pass3_kernel<<<NSAMP / 256, 256, 0, stream>>>(xyz, points, cent, gidx,
                                                w0, b0, w1, b1, w2, b2, stats);
  finalize2_kernel<<<1, 128, 0, stream>>>(stats, g2, be2);
  pass4_kernel<<<NSAMP / 256, 256, 0, stream>>>(xyz, points, cent, gidx,
                                                w0, b0, w1, b1, w2, b2, stats,
                                                outnp);
}